// Round 11
// baseline (226.815 us; speedup 1.0000x reference)
//
#include <hip/hip_runtime.h>
#include <math.h>

// MoE gate: logits = x[16384,2048] @ W^T[2048,64]; top-8; softmax over top-8.
//
// Round-13: round-12's decoupled counted-vmcnt register pipeline, refit into
// a 128-VGPR budget so it runs at 4 waves/SIMD (round-12 needed (512,1) ->
// 256-VGPR class -> 2 waves/SIMD; VGPR occupancy ladder: <=128 -> 16
// waves/CU, (128,256] -> 8). Wave tile shrinks to 16 tokens:
//   grid 512 (TOK=32/block), block = 512 thr = 8 waves = (tp in 2)x(kq in 4);
//   wave: 16 tok x 64 exp x 512 k = 16 K-steps of 32.
//   B pipelined at HALF-STEP granularity: bA/bB = 6 frags (24 VGPR) each;
//   schedule per step: split3(x(s)) | MFMA nt{0,1} w/ bA | issue bA<-B(s+1)
//   half0 | issue x(s+2) | MFMA nt{2,3} w/ bB | issue bB<-B(s+1) half1.
//   Steady-state waits are vmcnt(8) (6 B + 2 x newer always in flight) —
//   never drains to 0 mid-loop. x keeps depth-2 prefetch (HBM ~900cyc, lead
//   = 2 steps x 4-wave TLP).
//   Budget: acc 16 + B 48 + x 24 + ah/am/al 12 + addr/temps ~20 ≈ 120 <= 128
//   (launch_bounds(512,2) cap; WRITE_SIZE is the spill tripwire).
//
// Proven numerics (unchanged): v_mfma_f32_16x16x32_bf16, 3-way bf16 split
// x=xh+xm+xl / W likewise, 6 products hh,mh,hm,lh,hl,mm (~2^-25 rel error).
// Prologue splits W into d_ws (768 KB) in B-frag order (frag (ksg,nt,sp) =
// 1024 B; lane l dwordx4 at +l*16; n = nt*16+(l&15), k = ksg*32+(l>>4)*8+
// {2p+h}, pair-order identical to A packing). Wave kq uses ksg = kq*16+s.
// C/D layout (m89-verified): col(=expert)=lane&15, row(=token)=(lane>>4)*4+reg.

#define H_DIM 2048
#define N_EXP 64
#define TOPK 8
#define TOK 32
#define NSTEP 16

typedef __attribute__((ext_vector_type(8))) short bf16x8;
typedef __attribute__((ext_vector_type(4))) float f32x4;

union FragU { uint4 q; unsigned u[4]; bf16x8 s; };

__device__ inline unsigned cvt_pk_bf16(float lo, float hi) {
  unsigned d;
  asm("v_cvt_pk_bf16_f32 %0, %1, %2" : "=v"(d) : "v"(lo), "v"(hi));
  return d;
}

// split 8 f32 (one A/B fragment worth) into 3 packed-bf16 fragments
__device__ inline void split3(const float* e, unsigned* dh, unsigned* dm,
                              unsigned* dl) {
#pragma unroll
  for (int p = 0; p < 4; ++p) {
    const float f0 = e[2 * p], f1 = e[2 * p + 1];
    const unsigned h = cvt_pk_bf16(f0, f1);
    const float r0 = f0 - __uint_as_float(h << 16);
    const float r1 = f1 - __uint_as_float(h & 0xffff0000u);
    const unsigned m = cvt_pk_bf16(r0, r1);
    const float s0 = r0 - __uint_as_float(m << 16);
    const float s1 = r1 - __uint_as_float(m & 0xffff0000u);
    dl[p] = cvt_pk_bf16(s0, s1);
    dh[p] = h;
    dm[p] = m;
  }
}

// ---- prologue: W[64][2048] f32 -> ws bf16x3 in B-fragment order ----
__global__ __launch_bounds__(256) void w_split_kernel(
    const float* __restrict__ w, uint4* __restrict__ ws) {
  const int id = blockIdx.x * 256 + threadIdx.x;  // 16384 threads
  const int l = id & 63;
  const int nt = (id >> 6) & 3;
  const int ksg = id >> 8;  // 0..63
  const int n = nt * 16 + (l & 15);
  const int kb = ksg * 32 + ((l >> 4) << 3);
  const float* wr = w + (size_t)n * H_DIM + kb;
  const float4 a = *(const float4*)(wr);
  const float4 b = *(const float4*)(wr + 4);
  const float e[8] = {a.x, a.y, a.z, a.w, b.x, b.y, b.z, b.w};
  unsigned dh[4], dm[4], dl[4];
  split3(e, dh, dm, dl);
  const int base = (ksg * 12 + nt * 3) * 64 + l;  // frag i=nt*3+sp stride 64
  ws[base] = make_uint4(dh[0], dh[1], dh[2], dh[3]);
  ws[base + 64] = make_uint4(dm[0], dm[1], dm[2], dm[3]);
  ws[base + 128] = make_uint4(dl[0], dl[1], dl[2], dl[3]);
}

// ---- main-loop helpers (array-reference params keep indices static) ----
__device__ __forceinline__ void load_b6(uint4 (&dst)[6], const uint4* wb,
                                        int off) {
#pragma unroll
  for (int i = 0; i < 6; ++i) dst[i] = wb[(off + i) * 64];
}

__device__ __forceinline__ void load_x2(float4 (&dst)[2], const float* p) {
  dst[0] = *(const float4*)(p);
  dst[1] = *(const float4*)(p + 4);
}

// 12 MFMAs: one half (2 n-tiles) x 6 products
__device__ __forceinline__ void mfma_half(const bf16x8& ah, const bf16x8& am,
                                          const bf16x8& al,
                                          const uint4 (&bfr)[6],
                                          f32x4 (&acc)[4], int nt0) {
#pragma unroll
  for (int j = 0; j < 2; ++j) {
    FragU bh, bm, bl;
    bh.q = bfr[j * 3 + 0];
    bm.q = bfr[j * 3 + 1];
    bl.q = bfr[j * 3 + 2];
    f32x4 c = acc[nt0 + j];
    c = __builtin_amdgcn_mfma_f32_16x16x32_bf16(ah, bh.s, c, 0, 0, 0);
    c = __builtin_amdgcn_mfma_f32_16x16x32_bf16(am, bh.s, c, 0, 0, 0);
    c = __builtin_amdgcn_mfma_f32_16x16x32_bf16(ah, bm.s, c, 0, 0, 0);
    c = __builtin_amdgcn_mfma_f32_16x16x32_bf16(al, bh.s, c, 0, 0, 0);
    c = __builtin_amdgcn_mfma_f32_16x16x32_bf16(ah, bl.s, c, 0, 0, 0);
    c = __builtin_amdgcn_mfma_f32_16x16x32_bf16(am, bm.s, c, 0, 0, 0);
    acc[nt0 + j] = c;
  }
}

// ---- main kernel ----
__global__ __launch_bounds__(512, 2) void moe_gate_kernel(
    const float* __restrict__ x, const uint4* __restrict__ wf_g,
    float* __restrict__ out, int n_tokens) {
  __shared__ float part[8 * 1024];       // 32 KB: per-wave C fragments
  __shared__ float logits[N_EXP * TOK];  // 8 KB

  const int tid = threadIdx.x;
  const int l = tid & 63;
  const int w = tid >> 6;
  const int tp = w & 1;   // token half (16 tokens each)
  const int kq = w >> 1;  // k quarter (512 k)
  const int t0 = blockIdx.x * TOK;

  // x A-frag address: row = t0+tp*16+(l&15), col = kq*512 + s*32 + (l>>4)*8
  const float* xp =
      x + (size_t)(t0 + tp * 16 + (l & 15)) * H_DIM + kq * 512 + ((l >> 4) << 3);
  const uint4* wbase = wf_g + (size_t)(kq * 16) * 768 + l;

  f32x4 acc[4];
#pragma unroll
  for (int nt = 0; nt < 4; ++nt) acc[nt] = (f32x4){0.f, 0.f, 0.f, 0.f};

  uint4 bA[6], bB[6];
  float4 xA[2], xB[2], xC[2];

  // prologue: B(0) both halves (L2-fast), then x(0), x(1)
  load_b6(bA, wbase, 0);
  load_b6(bB, wbase, 6);
  load_x2(xA, xp);
  load_x2(xB, xp + 32);

#pragma unroll 1
  for (int s = 0; s < NSTEP; ++s) {
    // split x(s) -> 3 A-frags (loaded 2 steps ago; vmcnt wait is deep)
    bf16x8 ah, am, al;
    {
      const float4 v0 = xA[0], v1 = xA[1];
      const float e[8] = {v0.x, v0.y, v0.z, v0.w, v1.x, v1.y, v1.z, v1.w};
      FragU uh, um, ul;
      split3(e, uh.u, um.u, ul.u);
      ah = uh.s;
      am = um.s;
      al = ul.s;
    }
    // half 0: consume bA (issued one half-step ago; 8 newer loads in
    // flight -> steady-state wait vmcnt(8), never 0)
    mfma_half(ah, am, al, bA, acc, 0);
    if (s + 1 < NSTEP) load_b6(bA, wbase + (size_t)(s + 1) * 768, 0);
    if (s + 2 < NSTEP) load_x2(xC, xp + (s + 2) * 32);
    // half 1: consume bB
    mfma_half(ah, am, al, bB, acc, 2);
    if (s + 1 < NSTEP) load_b6(bB, wbase + (size_t)(s + 1) * 768, 6);
    // rotate x prefetch (static-index moves)
    xA[0] = xB[0]; xA[1] = xB[1];
    xB[0] = xC[0]; xB[1] = xC[1];
  }

  // ---- store per-wave C fragments (1024 floats/wave); reduce; top-8 ----
#pragma unroll
  for (int nt = 0; nt < 4; ++nt)
    *(float4*)&part[w * 1024 + nt * 256 + l * 4] =
        make_float4(acc[nt][0], acc[nt][1], acc[nt][2], acc[nt][3]);
  __syncthreads();

  // logits[e][t32]: invert C/D mapping, sum the 4 k-quarters of each tp-half
  for (int z = tid; z < N_EXP * TOK; z += 512) {
    const int e = z >> 5, t32 = z & 31;
    const int tpz = t32 >> 4, r16 = t32 & 15;
    const int q = r16 >> 2, rz = r16 & 3;
    const int idx = (e >> 4) * 256 + (q * 16 + (e & 15)) * 4 + rz;
    float v = ((part[(0 * 2 + tpz) * 1024 + idx] +
                part[(1 * 2 + tpz) * 1024 + idx]) +
               (part[(2 * 2 + tpz) * 1024 + idx] +
                part[(3 * 2 + tpz) * 1024 + idx]));
    logits[z] = v;  // z = e*32 + t32
  }
  __syncthreads();

  if (tid >= TOK) return;  // 32 tokens: lanes 0..31 of wave 0

  // ---- per-lane top-8 over 64 logits (lane = token) ----
  float lg[N_EXP];
#pragma unroll
  for (int e = 0; e < N_EXP; ++e) lg[e] = logits[e * TOK + tid];

  float bw[TOPK];
  int bi[TOPK];
#pragma unroll
  for (int k = 0; k < TOPK; ++k) {
    float m = lg[0];
    int mi = 0;
#pragma unroll
    for (int e = 1; e < N_EXP; ++e) {
      if (lg[e] > m) {  // strict > keeps lowest index on tie (lax.top_k)
        m = lg[e];
        mi = e;
      }
    }
    bw[k] = m;
    bi[k] = mi;
#pragma unroll
    for (int e = 0; e < N_EXP; ++e)
      if (e == mi) lg[e] = -INFINITY;
  }

  // softmax over top-8 == full softmax renormalized to top-8 (exact)
  const float mx = bw[0];
  float ew[TOPK];
  float s = 0.f;
#pragma unroll
  for (int k = 0; k < TOPK; ++k) {
    ew[k] = expf(bw[k] - mx);
    s += ew[k];
  }
  const float inv = 1.f / s;

  float4 w0, w1, i0, i1;
  w0.x = ew[0] * inv; w0.y = ew[1] * inv; w0.z = ew[2] * inv; w0.w = ew[3] * inv;
  w1.x = ew[4] * inv; w1.y = ew[5] * inv; w1.z = ew[6] * inv; w1.w = ew[7] * inv;
  i0.x = (float)bi[0]; i0.y = (float)bi[1]; i0.z = (float)bi[2]; i0.w = (float)bi[3];
  i1.x = (float)bi[4]; i1.y = (float)bi[5]; i1.z = (float)bi[6]; i1.w = (float)bi[7];

  const int t = t0 + tid;
  float4* ow = reinterpret_cast<float4*>(out + (size_t)t * TOPK);
  ow[0] = w0;
  ow[1] = w1;
  float4* oi =
      reinterpret_cast<float4*>(out + (size_t)n_tokens * TOPK + (size_t)t * TOPK);
  oi[0] = i0;
  oi[1] = i1;
}

extern "C" void kernel_launch(void* const* d_in, const int* in_sizes, int n_in,
                              void* d_out, int out_size, void* d_ws,
                              size_t ws_size, hipStream_t stream) {
  const float* x = (const float*)d_in[0];
  const float* w = (const float*)d_in[1];
  float* out = (float*)d_out;
  const int n_tokens = in_sizes[0] / H_DIM;  // 16384
  // prologue: split W into B-fragment-ordered bf16x3 (768 KB in d_ws)
  w_split_kernel<<<64, 256, 0, stream>>>(w, (uint4*)d_ws);
  const int n_blocks = n_tokens / TOK;  // 512
  moe_gate_kernel<<<n_blocks, 512, 0, stream>>>(x, (const uint4*)d_ws, out,
                                                n_tokens);
}